// Round 1
// baseline (192.655 us; speedup 1.0000x reference)
//
#include <hip/hip_runtime.h>
#include <math.h>

#define FEAT 4096
#define BATCH 4096

// Kernel 1: one block per row. Computes relu(2 - ||o1-o3|| + ||o1-o2||) per row.
// ILP version: all 12 float4 loads issued back-to-back into named registers
// before any arithmetic, so ~192 B/thread are in flight instead of ~48 B
// (VGPR=28 in the previous build serialized the loads into 4 rounds).
__global__ __launch_bounds__(256) void row_dist_kernel(
    const float* __restrict__ o1, const float* __restrict__ o2,
    const float* __restrict__ o3, float* __restrict__ row_out)
{
    const int row = blockIdx.x;
    const int tid = threadIdx.x;
    const float4* p1 = (const float4*)(o1 + (size_t)row * FEAT) + tid;
    const float4* p2 = (const float4*)(o2 + (size_t)row * FEAT) + tid;
    const float4* p3 = (const float4*)(o3 + (size_t)row * FEAT) + tid;

    // FEAT/4 = 1024 float4 per row; 256 threads -> 4 each, coalesced stride-256.
    // Issue order a,b,c per k so compute can begin at vmcnt(9) while the
    // remaining 9 loads are still outstanding.
    const float4 a0 = p1[0];   const float4 b0 = p2[0];   const float4 c0 = p3[0];
    const float4 a1 = p1[256]; const float4 b1 = p2[256]; const float4 c1 = p3[256];
    const float4 a2 = p1[512]; const float4 b2 = p2[512]; const float4 c2 = p3[512];
    const float4 a3 = p1[768]; const float4 b3 = p2[768]; const float4 c3 = p3[768];

    float s13 = 0.0f, s12 = 0.0f;
    float d;
    d = a0.x - c0.x; s13 = fmaf(d, d, s13);
    d = a0.y - c0.y; s13 = fmaf(d, d, s13);
    d = a0.z - c0.z; s13 = fmaf(d, d, s13);
    d = a0.w - c0.w; s13 = fmaf(d, d, s13);
    d = a0.x - b0.x; s12 = fmaf(d, d, s12);
    d = a0.y - b0.y; s12 = fmaf(d, d, s12);
    d = a0.z - b0.z; s12 = fmaf(d, d, s12);
    d = a0.w - b0.w; s12 = fmaf(d, d, s12);

    d = a1.x - c1.x; s13 = fmaf(d, d, s13);
    d = a1.y - c1.y; s13 = fmaf(d, d, s13);
    d = a1.z - c1.z; s13 = fmaf(d, d, s13);
    d = a1.w - c1.w; s13 = fmaf(d, d, s13);
    d = a1.x - b1.x; s12 = fmaf(d, d, s12);
    d = a1.y - b1.y; s12 = fmaf(d, d, s12);
    d = a1.z - b1.z; s12 = fmaf(d, d, s12);
    d = a1.w - b1.w; s12 = fmaf(d, d, s12);

    d = a2.x - c2.x; s13 = fmaf(d, d, s13);
    d = a2.y - c2.y; s13 = fmaf(d, d, s13);
    d = a2.z - c2.z; s13 = fmaf(d, d, s13);
    d = a2.w - c2.w; s13 = fmaf(d, d, s13);
    d = a2.x - b2.x; s12 = fmaf(d, d, s12);
    d = a2.y - b2.y; s12 = fmaf(d, d, s12);
    d = a2.z - b2.z; s12 = fmaf(d, d, s12);
    d = a2.w - b2.w; s12 = fmaf(d, d, s12);

    d = a3.x - c3.x; s13 = fmaf(d, d, s13);
    d = a3.y - c3.y; s13 = fmaf(d, d, s13);
    d = a3.z - c3.z; s13 = fmaf(d, d, s13);
    d = a3.w - c3.w; s13 = fmaf(d, d, s13);
    d = a3.x - b3.x; s12 = fmaf(d, d, s12);
    d = a3.y - b3.y; s12 = fmaf(d, d, s12);
    d = a3.z - b3.z; s12 = fmaf(d, d, s12);
    d = a3.w - b3.w; s12 = fmaf(d, d, s12);

    // wave(64)-level butterfly reduce
    #pragma unroll
    for (int off = 32; off > 0; off >>= 1) {
        s13 += __shfl_down(s13, off, 64);
        s12 += __shfl_down(s12, off, 64);
    }

    __shared__ float ls13[4];
    __shared__ float ls12[4];
    const int wave = tid >> 6;
    const int lane = tid & 63;
    if (lane == 0) { ls13[wave] = s13; ls12[wave] = s12; }
    __syncthreads();
    if (tid == 0) {
        const float t13 = ls13[0] + ls13[1] + ls13[2] + ls13[3];
        const float t12 = ls12[0] + ls12[1] + ls12[2] + ls12[3];
        const float compare = 2.0f - sqrtf(t13) + sqrtf(t12);
        row_out[row] = fmaxf(compare, 0.0f);
    }
}

// Kernel 2: reduce the BATCH row values, scale by BATCH (broadcast-sum semantics).
// UNCHANGED: current summation order gives absmax == 0.0 vs the JAX reference.
__global__ __launch_bounds__(1024) void final_reduce_kernel(
    const float* __restrict__ row_vals, float* __restrict__ out)
{
    const int tid = threadIdx.x;
    float s = 0.0f;
    #pragma unroll
    for (int k = 0; k < BATCH / 1024; ++k) s += row_vals[tid + k * 1024];

    #pragma unroll
    for (int off = 32; off > 0; off >>= 1) s += __shfl_down(s, off, 64);

    __shared__ float ls[16];
    const int wave = tid >> 6;
    const int lane = tid & 63;
    if (lane == 0) ls[wave] = s;
    __syncthreads();
    if (tid == 0) {
        float t = 0.0f;
        #pragma unroll
        for (int i = 0; i < 16; ++i) t += ls[i];
        out[0] = t * (float)BATCH;
    }
}

extern "C" void kernel_launch(void* const* d_in, const int* in_sizes, int n_in,
                              void* d_out, int out_size, void* d_ws, size_t ws_size,
                              hipStream_t stream) {
    const float* o1 = (const float*)d_in[0];
    const float* o2 = (const float*)d_in[1];
    const float* o3 = (const float*)d_in[2];
    float* row_ws = (float*)d_ws;          // BATCH floats of scratch
    float* out = (float*)d_out;            // single fp32 scalar

    row_dist_kernel<<<BATCH, 256, 0, stream>>>(o1, o2, o3, row_ws);
    final_reduce_kernel<<<1, 1024, 0, stream>>>(row_ws, out);
}

// Round 2
// 191.996 us; speedup vs baseline: 1.0034x; 1.0034x over previous
//
#include <hip/hip_runtime.h>
#include <math.h>

#define FEAT 4096
#define BATCH 4096

typedef __attribute__((address_space(3))) unsigned int lds_u32_t;
typedef __attribute__((address_space(1))) unsigned int glob_u32_t;

// Kernel 1: one block per row. Computes relu(2 - ||o1-o3|| + ||o1-o2||) per row.
//
// MLP via direct-to-LDS staging: __builtin_amdgcn_global_load_lds(width=16)
// carries no VGPR cost, so all 12 wave-instructions (48/block, 1 KiB each)
// stay outstanding until the barrier drain. Round-0 lesson: the compiler
// re-serializes register loads to keep VGPR=28, capping in-flight bytes;
// async LDS loads are the only source-level way to force deep MLP.
__global__ __launch_bounds__(256) void row_dist_kernel(
    const float* __restrict__ o1, const float* __restrict__ o2,
    const float* __restrict__ o3, float* __restrict__ row_out)
{
    __shared__ __align__(16) float lA[FEAT];   // 16 KiB
    __shared__ __align__(16) float lB[FEAT];   // 16 KiB
    __shared__ __align__(16) float lC[FEAT];   // 16 KiB  -> 3 blocks/CU resident
    __shared__ float ls13[4];
    __shared__ float ls12[4];

    const int row = blockIdx.x;
    const int tid = threadIdx.x;
    const int wave = tid >> 6;
    const int lane = tid & 63;

    const float* gA = o1 + (size_t)row * FEAT;
    const float* gB = o2 + (size_t)row * FEAT;
    const float* gC = o3 + (size_t)row * FEAT;

    // Stage 48 KiB. Each wave-instruction moves 64 lanes x 16 B = 1 KiB.
    // wave w owns chunks w*4 .. w*4+3 of each array.
    // LDS dest must be WAVE-UNIFORM (HW adds lane*16); global src is per-lane.
    #pragma unroll
    for (int i = 0; i < 4; ++i) {
        const int c = wave * 4 + i;            // chunk id 0..15
        const int cbase = c * 256;             // float offset of chunk (uniform)
        const int goff = cbase + lane * 4;     // this lane's 16 B (per-lane)
        __builtin_amdgcn_global_load_lds((const glob_u32_t*)(gA + goff),
                                         (lds_u32_t*)(lA + cbase), 16, 0, 0);
        __builtin_amdgcn_global_load_lds((const glob_u32_t*)(gB + goff),
                                         (lds_u32_t*)(lB + cbase), 16, 0, 0);
        __builtin_amdgcn_global_load_lds((const glob_u32_t*)(gC + goff),
                                         (lds_u32_t*)(lC + cbase), 16, 0, 0);
    }
    __syncthreads();   // compiler emits s_waitcnt vmcnt(0) before s_barrier

    const float4* pA = (const float4*)lA;
    const float4* pB = (const float4*)lB;
    const float4* pC = (const float4*)lC;

    float s13 = 0.0f, s12 = 0.0f;
    #pragma unroll
    for (int k = 0; k < 4; ++k) {
        const int idx = tid + k * 256;
        const float4 a = pA[idx];
        const float4 b = pB[idx];
        const float4 c = pC[idx];
        float d;
        d = a.x - c.x; s13 = fmaf(d, d, s13);
        d = a.y - c.y; s13 = fmaf(d, d, s13);
        d = a.z - c.z; s13 = fmaf(d, d, s13);
        d = a.w - c.w; s13 = fmaf(d, d, s13);
        d = a.x - b.x; s12 = fmaf(d, d, s12);
        d = a.y - b.y; s12 = fmaf(d, d, s12);
        d = a.z - b.z; s12 = fmaf(d, d, s12);
        d = a.w - b.w; s12 = fmaf(d, d, s12);
    }

    // wave(64)-level butterfly reduce
    #pragma unroll
    for (int off = 32; off > 0; off >>= 1) {
        s13 += __shfl_down(s13, off, 64);
        s12 += __shfl_down(s12, off, 64);
    }

    if (lane == 0) { ls13[wave] = s13; ls12[wave] = s12; }
    __syncthreads();
    if (tid == 0) {
        const float t13 = ls13[0] + ls13[1] + ls13[2] + ls13[3];
        const float t12 = ls12[0] + ls12[1] + ls12[2] + ls12[3];
        const float compare = 2.0f - sqrtf(t13) + sqrtf(t12);
        row_out[row] = fmaxf(compare, 0.0f);
    }
}

// Kernel 2: reduce the BATCH row values, scale by BATCH (broadcast-sum semantics).
// UNCHANGED: current summation order gives absmax == 0.0 vs the JAX reference.
__global__ __launch_bounds__(1024) void final_reduce_kernel(
    const float* __restrict__ row_vals, float* __restrict__ out)
{
    const int tid = threadIdx.x;
    float s = 0.0f;
    #pragma unroll
    for (int k = 0; k < BATCH / 1024; ++k) s += row_vals[tid + k * 1024];

    #pragma unroll
    for (int off = 32; off > 0; off >>= 1) s += __shfl_down(s, off, 64);

    __shared__ float ls[16];
    const int wave = tid >> 6;
    const int lane = tid & 63;
    if (lane == 0) ls[wave] = s;
    __syncthreads();
    if (tid == 0) {
        float t = 0.0f;
        #pragma unroll
        for (int i = 0; i < 16; ++i) t += ls[i];
        out[0] = t * (float)BATCH;
    }
}

extern "C" void kernel_launch(void* const* d_in, const int* in_sizes, int n_in,
                              void* d_out, int out_size, void* d_ws, size_t ws_size,
                              hipStream_t stream) {
    const float* o1 = (const float*)d_in[0];
    const float* o2 = (const float*)d_in[1];
    const float* o3 = (const float*)d_in[2];
    float* row_ws = (float*)d_ws;          // BATCH floats of scratch
    float* out = (float*)d_out;            // single fp32 scalar

    row_dist_kernel<<<BATCH, 256, 0, stream>>>(o1, o2, o3, row_ws);
    final_reduce_kernel<<<1, 1024, 0, stream>>>(row_ws, out);
}